// Round 1
// baseline (263.577 us; speedup 1.0000x reference)
//
#include <hip/hip_runtime.h>
#include <math.h>

#define INPUT  28
#define HIDDEN 64
#define NOUT   10
#define BLK    256

// out[b,:] = fc_w @ tanh(w_ih @ x[b,27,:] + b_ih + b_hh) + fc_b
// (hx == 0 so the w_hh term vanishes; only row 27 of x is ever read)
__global__ __launch_bounds__(BLK) void rnn_fused(
    const float* __restrict__ x,
    const float* __restrict__ w_ih,
    const float* __restrict__ b_ih,
    const float* __restrict__ b_hh,
    const float* __restrict__ fc_w,
    const float* __restrict__ fc_b,
    float* __restrict__ out,
    int B)
{
    __shared__ float s_wih[HIDDEN * INPUT];   // [h][c], 7 KiB
    __shared__ float s_fcw[HIDDEN * NOUT];    // transposed [h][o], 2.5 KiB
    __shared__ float s_bias[HIDDEN];          // b_ih + b_hh
    __shared__ float s_fcb[NOUT];

    const int t = threadIdx.x;

    // Stage weights into LDS (coalesced; ~10 KB per block, L2-cached after block 0)
    for (int i = t; i < HIDDEN * INPUT; i += BLK) s_wih[i] = w_ih[i];
    for (int i = t; i < HIDDEN * NOUT; i += BLK) {
        int h = i / NOUT, o = i - h * NOUT;
        s_fcw[i] = fc_w[o * HIDDEN + h];      // transpose: [h][o]
    }
    if (t < HIDDEN) s_bias[t] = b_ih[t] + b_hh[t];
    if (t < NOUT)   s_fcb[t]  = fc_b[t];
    __syncthreads();

    const int b = blockIdx.x * BLK + t;
    if (b >= B) return;

    // Load x[b, 27, 0:28] — 7 aligned float4s (756 and 784 are multiples of 4)
    float inp[INPUT];
    const float4* xp = reinterpret_cast<const float4*>(x + (size_t)b * 784 + 756);
    #pragma unroll
    for (int k = 0; k < 7; ++k) {
        float4 v = xp[k];
        inp[4*k+0] = v.x; inp[4*k+1] = v.y; inp[4*k+2] = v.z; inp[4*k+3] = v.w;
    }

    // acc[o] accumulates the FC output; hidden values are consumed immediately
    float acc[NOUT];
    #pragma unroll
    for (int o = 0; o < NOUT; ++o) acc[o] = s_fcb[o];

    #pragma unroll 4
    for (int h = 0; h < HIDDEN; ++h) {
        float s = s_bias[h];
        #pragma unroll
        for (int c = 0; c < INPUT; ++c)
            s = fmaf(s_wih[h * INPUT + c], inp[c], s);   // LDS broadcast reads
        const float th = tanhf(s);
        #pragma unroll
        for (int o = 0; o < NOUT; ++o)
            acc[o] = fmaf(s_fcw[h * NOUT + o], th, acc[o]);
    }

    // 40 contiguous bytes per thread
    float* op = out + (size_t)b * NOUT;
    #pragma unroll
    for (int o = 0; o < NOUT; ++o) op[o] = acc[o];
}

extern "C" void kernel_launch(void* const* d_in, const int* in_sizes, int n_in,
                              void* d_out, int out_size, void* d_ws, size_t ws_size,
                              hipStream_t stream)
{
    const float* x    = (const float*)d_in[0];
    const float* w_ih = (const float*)d_in[1];
    // d_in[2] = w_hh — mathematically dead (hx == 0)
    const float* b_ih = (const float*)d_in[3];
    const float* b_hh = (const float*)d_in[4];
    const float* fc_w = (const float*)d_in[5];
    const float* fc_b = (const float*)d_in[6];
    float* out = (float*)d_out;

    const int B = in_sizes[0] / (28 * 28);
    const int grid = (B + BLK - 1) / BLK;
    rnn_fused<<<grid, BLK, 0, stream>>>(x, w_ih, b_ih, b_hh, fc_w, fc_b, out, B);
}